// Round 16
// baseline (292.719 us; speedup 1.0000x reference)
//
#include <hip/hip_runtime.h>
#include <math.h>

// VQ-VAE EMA vector quantizer for MI355X (gfx950).
// Round 16: 16 rows/wave (2048 blocks -> 8 blocks/CU -> 8 waves/SIMD residency, proved
// by round 15's 77% occupancy) + __launch_bounds__(256,1) (the only VGPR budget this
// toolchain doesn't spill under: (256,1)->60-64 clean, default->40-52 spill,
// (256,8)->32 spill). 16-row kernel needs ~55 VGPR <= 64 -> full occupancy unforced.
// np-chain emulation + quantized flag margin (round 13, verified).
#define NROWS 131072          // 32*4096
#define DIM 64
#define NCODE 512
#define FLAG_CAP 32768

// d_out float offsets
#define OUT_ZQ    0
#define OUT_LOSS  8388608
#define OUT_CODES 8388609
#define OUT_ECS   8519681
#define OUT_EMAW  8520193
#define OUT_EMB   8552961

// workspace byte offsets
#define WS_LOSS    0         // double
#define WS_N       8         // float
#define WS_FLAGC   12        // int
#define WS_COUNTS  16        // int[512]
#define WS_OFFSETS 2064      // int[512]
#define WS_CURSOR  4112      // int[512]
#define WS_CSUM    6160      // float[512]
#define WS_EHI     8208      // ushort[512*64]
#define WS_ELO     73744     // ushort[512*64]
#define WS_CODESI  139280    // int[131072]; dead after k_scatter -> reused as dw4
#define WS_DW4     139280    // float[4*512*64]
#define WS_BUCKET  663568    // int[131072]; before k_scatter reused as flagR
#define WS_FLAGR   663568
#define WS_BYTES   1187856

#define DECAY_C ((float)0.9)
#define OMD_C   ((float)(1.0 - 0.9))
#define EPS_C   ((float)1e-5)

typedef float f32x4 __attribute__((ext_vector_type(4)));
typedef short short8v __attribute__((ext_vector_type(8)));

__device__ __forceinline__ unsigned short bf16_rne_bits(float f) {
    unsigned int u = __float_as_uint(f);
    unsigned int r = u + 0x7fffu + ((u >> 16) & 1u);
    return (unsigned short)(r >> 16);
}

// numpy pairwise sum (scalar unroll-8 path, n=64) of v[d]*v[d], f32, no contraction.
__device__ __forceinline__ float np_pairwise64_sq(const float* v) {
    float r[8];
#pragma unroll
    for (int j = 0; j < 8; ++j) r[j] = __fmul_rn(v[j], v[j]);
#pragma unroll
    for (int b = 1; b < 8; ++b) {
#pragma unroll
        for (int j = 0; j < 8; ++j)
            r[j] = __fadd_rn(r[j], __fmul_rn(v[8 * b + j], v[8 * b + j]));
    }
    return __fadd_rn(__fadd_rn(__fadd_rn(r[0], r[1]), __fadd_rn(r[2], r[3])),
                     __fadd_rn(__fadd_rn(r[4], r[5]), __fadd_rn(r[6], r[7])));
}

// ---- csum + bf16 split + workspace zeroing (memset dispatch folded in) ----
__global__ void k_csum(const float* __restrict__ emb, float* __restrict__ csum,
                       unsigned short* __restrict__ ehi, unsigned short* __restrict__ elo,
                       int* __restrict__ counts, int* __restrict__ flagC,
                       double* __restrict__ lossAcc, float* __restrict__ n_out) {
    int k = blockIdx.x * blockDim.x + threadIdx.x;
    if (k >= NCODE) return;
    counts[k] = 0;
    if (k == 0) { *flagC = 0; *lossAcc = 0.0; *n_out = 0.f; }
    float e[DIM];
#pragma unroll
    for (int d = 0; d < DIM; d += 4) {
        float4 v = *reinterpret_cast<const float4*>(emb + (size_t)k * DIM + d);
        e[d] = v.x; e[d + 1] = v.y; e[d + 2] = v.z; e[d + 3] = v.w;
    }
    csum[k] = np_pairwise64_sq(e);
#pragma unroll
    for (int d = 0; d < DIM; ++d) {
        unsigned short hb = bf16_rne_bits(e[d]);
        float hf = __uint_as_float((unsigned int)hb << 16);
        ehi[k * DIM + d] = hb;
        elo[k * DIM + d] = bf16_rne_bits(e[d] - hf);
    }
}

#define CVTE(H, L, j, val) { \
    unsigned int ub = __float_as_uint(val); \
    unsigned int rr = ub + 0x7fffu + ((ub >> 16) & 1u); \
    unsigned short hb = (unsigned short)(rr >> 16); \
    float hf2 = __uint_as_float(((unsigned int)hb) << 16); \
    float lof = (val) - hf2; \
    unsigned int ul = __float_as_uint(lof); \
    unsigned int rl = ul + 0x7fffu + ((ul >> 16) & 1u); \
    H[j] = (short)hb; L[j] = (short)(rl >> 16); }

// ---- MFMA scores (np-chain emulated) + fused z_q/loss/hist; 16 rows/wave ----
__global__ __launch_bounds__(256, 1) void k_mfma(
        const float* __restrict__ ze, const float* __restrict__ emb,
        const unsigned short* __restrict__ ehi, const unsigned short* __restrict__ elo,
        const float* __restrict__ csum, float* __restrict__ out,
        int* __restrict__ codes_i, int* __restrict__ counts,
        double* __restrict__ lossAcc, int* __restrict__ flagC, int* __restrict__ flagR) {
    __shared__ float cs[NCODE];
    __shared__ int h[NCODE];
    __shared__ float A_s[64];
    __shared__ int code_s[64];
    __shared__ double ls[4];
    int tid = threadIdx.x;
    for (int i = tid; i < NCODE; i += 256) { cs[i] = csum[i]; h[i] = 0; }
    // A prepass: np-pairwise ||x||^2 for this block's 64 rows (verified bit path)
    if (tid < 64) {
        const float* xr = ze + (size_t)(blockIdx.x * 64 + tid) * DIM;
        float xv[DIM];
#pragma unroll
        for (int d = 0; d < DIM; d += 4) {
            float4 v = *reinterpret_cast<const float4*>(xr + d);
            xv[d] = v.x; xv[d + 1] = v.y; xv[d + 2] = v.z; xv[d + 3] = v.w;
        }
        A_s[tid] = np_pairwise64_sq(xv);
    }
    __syncthreads();

    int wid = tid >> 6;
    int lane = tid & 63;
    int r16 = lane & 15;
    int kg = lane >> 4;                 // k-group 0..3 (8 k-elements each)
    int rowbase = blockIdx.x * 64 + wid * 16;

    // per-lane A values for the 4 reg output rows
    float Ar[4];
#pragma unroll
    for (int reg = 0; reg < 4; ++reg)
        Ar[reg] = A_s[wid * 16 + 4 * kg + reg];

    // A-fragments: [k-half], hi and lo planes (rows rowbase + r16)
    short8v ahi[2], alo[2];
#define LOADA(hf) { \
        const float4* ap = reinterpret_cast<const float4*>( \
            ze + (size_t)(rowbase + r16) * DIM + (hf) * 32 + 8 * kg); \
        float4 u = ap[0], w = ap[1]; \
        CVTE(ahi[hf], alo[hf], 0, u.x) CVTE(ahi[hf], alo[hf], 1, u.y) \
        CVTE(ahi[hf], alo[hf], 2, u.z) CVTE(ahi[hf], alo[hf], 3, u.w) \
        CVTE(ahi[hf], alo[hf], 4, w.x) CVTE(ahi[hf], alo[hf], 5, w.y) \
        CVTE(ahi[hf], alo[hf], 6, w.z) CVTE(ahi[hf], alo[hf], 7, w.w) }
    LOADA(0) LOADA(1)

    float m1v[4] = {3.4e38f, 3.4e38f, 3.4e38f, 3.4e38f};
    float m2v[4] = {3.4e38f, 3.4e38f, 3.4e38f, 3.4e38f};
    int i1v[4] = {0, 0, 0, 0};

    // np-chain emulation: t~ = fl(fl(A - 2*dot) + csum); 2*dot = c+c exact
#define UPD(reg) { \
        float u = __fsub_rn(Ar[reg], __fadd_rn(c[reg], c[reg])); \
        float s = __fadd_rn(u, csv); \
        if (s < m1v[reg]) { m2v[reg] = m1v[reg]; m1v[reg] = s; i1v[reg] = codeIdx; } \
        else if (s < m2v[reg]) { m2v[reg] = s; } }

    for (int t = 0; t < 32; ++t) {
        const short8v* bh = reinterpret_cast<const short8v*>(
            ehi + (size_t)(t * 16 + r16) * DIM + 8 * kg);
        const short8v* bl = reinterpret_cast<const short8v*>(
            elo + (size_t)(t * 16 + r16) * DIM + 8 * kg);
        short8v bh0 = bh[0], bh1 = bh[4];      // k-half 0 (d 0..31), k-half 1 (d 32..63)
        short8v bl0 = bl[0], bl1 = bl[4];
        f32x4 c = {0.f, 0.f, 0.f, 0.f};
        c = __builtin_amdgcn_mfma_f32_16x16x32_bf16(ahi[0], bh0, c, 0, 0, 0);
        c = __builtin_amdgcn_mfma_f32_16x16x32_bf16(ahi[1], bh1, c, 0, 0, 0);
        c = __builtin_amdgcn_mfma_f32_16x16x32_bf16(alo[0], bh0, c, 0, 0, 0);
        c = __builtin_amdgcn_mfma_f32_16x16x32_bf16(alo[1], bh1, c, 0, 0, 0);
        c = __builtin_amdgcn_mfma_f32_16x16x32_bf16(ahi[0], bl0, c, 0, 0, 0);
        c = __builtin_amdgcn_mfma_f32_16x16x32_bf16(ahi[1], bl1, c, 0, 0, 0);
        float csv = cs[t * 16 + r16];
        int codeIdx = t * 16 + r16;
        UPD(0) UPD(1) UPD(2) UPD(3)
    }

    // reduce across the 16 lanes sharing a row (masks 1,2,4,8 stay in-group)
#define RED(reg, mask) { \
        float om1 = __shfl_xor(m1v[reg], mask); \
        int   oi  = __shfl_xor(i1v[reg], mask); \
        float om2 = __shfl_xor(m2v[reg], mask); \
        if (om1 < m1v[reg]) { \
            m2v[reg] = fminf(m1v[reg], om2); m1v[reg] = om1; i1v[reg] = oi; \
        } else if (om1 > m1v[reg]) { \
            m2v[reg] = fminf(m2v[reg], om1); \
        } else { \
            if (oi < i1v[reg]) i1v[reg] = oi; \
            m2v[reg] = m1v[reg]; } }
#define RED4(reg) RED(reg, 1) RED(reg, 2) RED(reg, 4) RED(reg, 8)
    RED4(0) RED4(1) RED4(2) RED4(3)

    if (r16 == 0) {
        // flag if margin <= 4 quanta of ulp(A): thr = A*6e-7 covers all attainable A
#define WOUT(reg) { \
        int lrow = wid * 16 + 4 * kg + (reg); \
        int row = blockIdx.x * 64 + lrow; \
        code_s[lrow] = i1v[reg]; \
        out[OUT_CODES + row] = (float)i1v[reg]; \
        codes_i[row] = i1v[reg]; \
        atomicAdd(&h[i1v[reg]], 1); \
        if (m2v[reg] - m1v[reg] < Ar[reg] * 6e-7f) { \
            int pos = atomicAdd(flagC, 1); \
            if (pos < FLAG_CAP) flagR[pos] = row; } }
        WOUT(0) WOUT(1) WOUT(2) WOUT(3)
    }
    __syncthreads();                        // code_s + h complete

    // provisional z_q + loss (rescue patches changed rows later)
    double lpart = 0.0;
#pragma unroll 4
    for (int r = 0; r < 16; ++r) {
        int code = code_s[wid * 16 + r];    // wave-uniform broadcast
        int row = rowbase + r;
        float x = ze[(size_t)row * DIM + lane];
        float e = emb[(size_t)code * DIM + lane];
        float tdiff = __fsub_rn(e, x);
        out[OUT_ZQ + (size_t)row * DIM + lane] = __fadd_rn(x, tdiff);
        lpart += (double)tdiff * tdiff;
    }
    for (int off = 32; off; off >>= 1) lpart += __shfl_down(lpart, off);
    if (lane == 0) ls[wid] = lpart;
    __syncthreads();
    if (tid == 0) atomicAdd(lossAcc, (ls[0] + ls[1]) + (ls[2] + ls[3]));
    for (int k = tid; k < NCODE; k += 256) {
        int cc = h[k];
        if (cc) atomicAdd(&counts[k], cc);
    }
}

// ---- rescue: bit-exact np-f32 re-argmin of flagged rows; patch if changed ----
__global__ __launch_bounds__(64) void k_rescue(
        const float* __restrict__ ze, const float* __restrict__ emb,
        const float* __restrict__ csum, float* __restrict__ out,
        int* __restrict__ codes_i, int* __restrict__ counts,
        double* __restrict__ lossAcc, const int* __restrict__ flagC,
        const int* __restrict__ flagR) {
    __shared__ float x2s[DIM];
    int nf = *flagC;
    if (nf > FLAG_CAP) nf = FLAG_CAP;
    int lane = threadIdx.x;
    for (int i = blockIdx.x; i < nf; i += gridDim.x) {
        int row = flagR[i];
        __syncthreads();
        float v = ze[(size_t)row * DIM + lane];
        x2s[lane] = __fadd_rn(v, v);
        __syncthreads();
        float r[8];
#pragma unroll
        for (int j = 0; j < 8; ++j) r[j] = __fmul_rn(x2s[j], x2s[j]);
#pragma unroll
        for (int b = 1; b < 8; ++b) {
#pragma unroll
            for (int j = 0; j < 8; ++j)
                r[j] = __fadd_rn(r[j], __fmul_rn(x2s[8 * b + j], x2s[8 * b + j]));
        }
        float A = __fmul_rn(0.25f,
            __fadd_rn(__fadd_rn(__fadd_rn(r[0], r[1]), __fadd_rn(r[2], r[3])),
                      __fadd_rn(__fadd_rn(r[4], r[5]), __fadd_rn(r[6], r[7]))));
        float m1 = 3.4e38f;
        int i1 = 0x7fffffff;
#pragma unroll
        for (int kk = 0; kk < 8; ++kk) {        // ascending k within lane
            int k = lane * 8 + kk;
            const float* e = emb + (size_t)k * DIM;
            float a = 0.f;
#pragma unroll
            for (int d = 0; d < DIM; ++d) a = __builtin_fmaf(x2s[d], e[d], a);
            float t = __fadd_rn(__fsub_rn(A, a), csum[k]);
            if (t < m1) { m1 = t; i1 = k; }
        }
        for (int off = 32; off; off >>= 1) {    // butterfly min, lowest-index tie-break
            float ov = __shfl_xor(m1, off);
            int oi = __shfl_xor(i1, off);
            if (ov < m1 || (ov == m1 && oi < i1)) { m1 = ov; i1 = oi; }
        }
        int oldc = codes_i[row];
        if (i1 != oldc) {                       // patch provisional results
            if (lane == 0) {
                codes_i[row] = i1;
                out[OUT_CODES + row] = (float)i1;
                atomicSub(&counts[oldc], 1);
                atomicAdd(&counts[i1], 1);
            }
            float x = __fmul_rn(0.5f, x2s[lane]);
            float en = emb[(size_t)i1 * DIM + lane];
            float eo = emb[(size_t)oldc * DIM + lane];
            float tn = __fsub_rn(en, x);
            float to = __fsub_rn(eo, x);
            out[OUT_ZQ + (size_t)row * DIM + lane] = __fadd_rn(x, tn);
            double dl = (double)tn * tn - (double)to * to;
            for (int off = 32; off; off >>= 1) dl += __shfl_down(dl, off);
            if (lane == 0) atomicAdd(lossAcc, dl);
        }
    }
}

// ---- one block: exclusive scan of counts -> offsets/cursor; new_ecs + n ----
__global__ __launch_bounds__(512) void k_scan(
        const int* __restrict__ counts, int* __restrict__ offsets, int* __restrict__ cursor,
        const float* __restrict__ ecs_in, float* __restrict__ out, float* __restrict__ n_out) {
    __shared__ int sa[NCODE], sb[NCODE];
    __shared__ float red[NCODE];
    int k = threadIdx.x;
    int c = counts[k];
    sa[k] = c;
    float v = __fadd_rn(__fmul_rn(ecs_in[k], DECAY_C), __fmul_rn((float)c, OMD_C));
    out[OUT_ECS + k] = v;
    red[k] = v;
    __syncthreads();
    int* src = sa;
    int* dst = sb;
    for (int off = 1; off < NCODE; off <<= 1) {
        dst[k] = (k >= off) ? src[k - off] + src[k] : src[k];
        __syncthreads();
        int* tp = src; src = dst; dst = tp;
    }
    offsets[k] = src[k] - c;
    cursor[k]  = src[k] - c;
    for (int s = NCODE / 2; s > 0; s >>= 1) {
        if (k < s) red[k] += red[k + s];
        __syncthreads();
    }
    if (k == 0) n_out[0] = red[0];
}

// ---- scatter rows into code buckets ----
__global__ __launch_bounds__(256) void k_scatter(
        const int* __restrict__ codes_i, int* __restrict__ cursor, int* __restrict__ bucket) {
    int row = blockIdx.x * 256 + threadIdx.x;
    int c = codes_i[row];
    int pos = atomicAdd(&cursor[c], 1);
    bucket[pos] = row;
}

// ---- per-code segmented sum, 4 blocks per code -> dw4 partials (no atomics) ----
__global__ __launch_bounds__(256) void k_dw(
        const float* __restrict__ ze, const int* __restrict__ bucket,
        const int* __restrict__ offsets, const int* __restrict__ counts,
        float* __restrict__ dw4) {
    __shared__ float p[4][DIM];
    int k = blockIdx.x >> 2;
    int q = blockIdx.x & 3;
    int w = threadIdx.x >> 6;
    int d = threadIdx.x & 63;
    int s = offsets[k];
    int n = counts[k];
    float acc0 = 0.f, acc1 = 0.f;
    int i = q + 4 * w;
    for (; i + 16 < n; i += 32) {
        int ra = bucket[s + i];
        int rb = bucket[s + i + 16];
        acc0 += ze[(size_t)ra * DIM + d];
        acc1 += ze[(size_t)rb * DIM + d];
    }
    if (i < n) acc0 += ze[(size_t)bucket[s + i] * DIM + d];
    p[w][d] = acc0 + acc1;
    __syncthreads();
    if (w == 0) dw4[((size_t)q * NCODE + k) * DIM + d] = (p[0][d] + p[1][d]) + (p[2][d] + p[3][d]);
}

// ---- new_ema_w, new_emb, loss ----
__global__ __launch_bounds__(256) void k_final(
        const float* __restrict__ ema_w, const float* __restrict__ dw4,
        const float* __restrict__ n_ptr, const double* __restrict__ lossAcc,
        float* __restrict__ out) {
    int i = blockIdx.x * blockDim.x + threadIdx.x;
    if (i >= NCODE * DIM) return;
    int k = i >> 6;
    float dsum = __fadd_rn(__fadd_rn(dw4[i], dw4[i + NCODE * DIM]),
                           __fadd_rn(dw4[i + 2 * NCODE * DIM], dw4[i + 3 * NCODE * DIM]));
    float w = __fadd_rn(__fmul_rn(ema_w[i], DECAY_C), __fmul_rn(dsum, OMD_C));
    out[OUT_EMAW + i] = w;
    float n = n_ptr[0];
    float necs = out[OUT_ECS + k];
    float cs = (necs + EPS_C) / (n + (float)NCODE * EPS_C) * n;
    out[OUT_EMB + i] = w / (cs + EPS_C);
    if (i == 0) out[OUT_LOSS] = (float)(0.1 * (lossAcc[0] / (double)((size_t)NROWS * DIM)));
}

extern "C" void kernel_launch(void* const* d_in, const int* in_sizes, int n_in,
                              void* d_out, int out_size, void* d_ws, size_t ws_size,
                              hipStream_t stream) {
    const float* ze   = (const float*)d_in[0];
    const float* emb  = (const float*)d_in[1];
    const float* ecs  = (const float*)d_in[2];
    const float* emaw = (const float*)d_in[3];
    float* out = (float*)d_out;
    char* ws = (char*)d_ws;
    double* lossAcc = (double*)(ws + WS_LOSS);
    float*  n_out   = (float*)(ws + WS_N);
    int*    flagC   = (int*)(ws + WS_FLAGC);
    int*    counts  = (int*)(ws + WS_COUNTS);
    int*    offsets = (int*)(ws + WS_OFFSETS);
    int*    cursor  = (int*)(ws + WS_CURSOR);
    float*  csum    = (float*)(ws + WS_CSUM);
    unsigned short* ehi = (unsigned short*)(ws + WS_EHI);
    unsigned short* elo = (unsigned short*)(ws + WS_ELO);
    int*    codes_i = (int*)(ws + WS_CODESI);
    float*  dw4     = (float*)(ws + WS_DW4);     // aliases codes_i (k_dw after k_scatter)
    int*    bucket  = (int*)(ws + WS_BUCKET);
    int*    flagR   = (int*)(ws + WS_FLAGR);     // aliases bucket (dead before k_scatter)

    hipLaunchKernelGGL(k_csum, dim3(2), dim3(256), 0, stream,
                       emb, csum, ehi, elo, counts, flagC, lossAcc, n_out);
    hipLaunchKernelGGL(k_mfma, dim3(NROWS / 64), dim3(256), 0, stream,
                       ze, emb, ehi, elo, csum, out, codes_i, counts, lossAcc, flagC, flagR);
    hipLaunchKernelGGL(k_rescue, dim3(2048), dim3(64), 0, stream,
                       ze, emb, csum, out, codes_i, counts, lossAcc, flagC, flagR);
    hipLaunchKernelGGL(k_scan, dim3(1), dim3(512), 0, stream,
                       counts, offsets, cursor, ecs, out, n_out);
    hipLaunchKernelGGL(k_scatter, dim3(NROWS / 256), dim3(256), 0, stream,
                       codes_i, cursor, bucket);
    hipLaunchKernelGGL(k_dw, dim3(NCODE * 4), dim3(256), 0, stream,
                       ze, bucket, offsets, counts, dw4);
    hipLaunchKernelGGL(k_final, dim3(NCODE * DIM / 256), dim3(256), 0, stream,
                       emaw, dw4, n_out, lossAcc, out);
}

// Round 17
// 239.100 us; speedup vs baseline: 1.2243x; 1.2243x over previous
//
#include <hip/hip_runtime.h>
#include <math.h>

// VQ-VAE EMA vector quantizer for MI355X (gfx950).
// Round 17: round-13 k_mfma geometry (32 rows/wave, 128 rows/block, 1024 blocks,
// __launch_bounds__(256,1) — the only non-spilling budget) + accumulator chain split:
// each 6-deep MFMA chain becomes two independent 3-chains summed once per tile
// (+8 VGPR, occupancy grid-limited so unchanged; dot error ~4e-7 << 7.6e-6 quantum,
// covered by the round-13 flag rule). np-chain emulation + quantized flag margin.
#define NROWS 131072          // 32*4096
#define DIM 64
#define NCODE 512
#define FLAG_CAP 32768

// d_out float offsets
#define OUT_ZQ    0
#define OUT_LOSS  8388608
#define OUT_CODES 8388609
#define OUT_ECS   8519681
#define OUT_EMAW  8520193
#define OUT_EMB   8552961

// workspace byte offsets
#define WS_LOSS    0         // double
#define WS_N       8         // float
#define WS_FLAGC   12        // int
#define WS_COUNTS  16        // int[512]
#define WS_OFFSETS 2064      // int[512]
#define WS_CURSOR  4112      // int[512]
#define WS_CSUM    6160      // float[512]
#define WS_EHI     8208      // ushort[512*64]
#define WS_ELO     73744     // ushort[512*64]
#define WS_CODESI  139280    // int[131072]; dead after k_scatter -> reused as dw4
#define WS_DW4     139280    // float[4*512*64]
#define WS_BUCKET  663568    // int[131072]; before k_scatter reused as flagR
#define WS_FLAGR   663568
#define WS_BYTES   1187856

#define DECAY_C ((float)0.9)
#define OMD_C   ((float)(1.0 - 0.9))
#define EPS_C   ((float)1e-5)

typedef float f32x4 __attribute__((ext_vector_type(4)));
typedef short short8v __attribute__((ext_vector_type(8)));

__device__ __forceinline__ unsigned short bf16_rne_bits(float f) {
    unsigned int u = __float_as_uint(f);
    unsigned int r = u + 0x7fffu + ((u >> 16) & 1u);
    return (unsigned short)(r >> 16);
}

// numpy pairwise sum (scalar unroll-8 path, n=64) of v[d]*v[d], f32, no contraction.
__device__ __forceinline__ float np_pairwise64_sq(const float* v) {
    float r[8];
#pragma unroll
    for (int j = 0; j < 8; ++j) r[j] = __fmul_rn(v[j], v[j]);
#pragma unroll
    for (int b = 1; b < 8; ++b) {
#pragma unroll
        for (int j = 0; j < 8; ++j)
            r[j] = __fadd_rn(r[j], __fmul_rn(v[8 * b + j], v[8 * b + j]));
    }
    return __fadd_rn(__fadd_rn(__fadd_rn(r[0], r[1]), __fadd_rn(r[2], r[3])),
                     __fadd_rn(__fadd_rn(r[4], r[5]), __fadd_rn(r[6], r[7])));
}

// ---- csum + bf16 split + workspace zeroing (memset dispatch folded in) ----
__global__ void k_csum(const float* __restrict__ emb, float* __restrict__ csum,
                       unsigned short* __restrict__ ehi, unsigned short* __restrict__ elo,
                       int* __restrict__ counts, int* __restrict__ flagC,
                       double* __restrict__ lossAcc, float* __restrict__ n_out) {
    int k = blockIdx.x * blockDim.x + threadIdx.x;
    if (k >= NCODE) return;
    counts[k] = 0;
    if (k == 0) { *flagC = 0; *lossAcc = 0.0; *n_out = 0.f; }
    float e[DIM];
#pragma unroll
    for (int d = 0; d < DIM; d += 4) {
        float4 v = *reinterpret_cast<const float4*>(emb + (size_t)k * DIM + d);
        e[d] = v.x; e[d + 1] = v.y; e[d + 2] = v.z; e[d + 3] = v.w;
    }
    csum[k] = np_pairwise64_sq(e);
#pragma unroll
    for (int d = 0; d < DIM; ++d) {
        unsigned short hb = bf16_rne_bits(e[d]);
        float hf = __uint_as_float((unsigned int)hb << 16);
        ehi[k * DIM + d] = hb;
        elo[k * DIM + d] = bf16_rne_bits(e[d] - hf);
    }
}

#define CVTE(H, L, j, val) { \
    unsigned int ub = __float_as_uint(val); \
    unsigned int rr = ub + 0x7fffu + ((ub >> 16) & 1u); \
    unsigned short hb = (unsigned short)(rr >> 16); \
    float hf2 = __uint_as_float(((unsigned int)hb) << 16); \
    float lof = (val) - hf2; \
    unsigned int ul = __float_as_uint(lof); \
    unsigned int rl = ul + 0x7fffu + ((ul >> 16) & 1u); \
    H[j] = (short)hb; L[j] = (short)(rl >> 16); }

// ---- MFMA scores (np-chain emulated, split accumulators) + fused z_q/loss/hist ----
__global__ __launch_bounds__(256, 1) void k_mfma(
        const float* __restrict__ ze, const float* __restrict__ emb,
        const unsigned short* __restrict__ ehi, const unsigned short* __restrict__ elo,
        const float* __restrict__ csum, float* __restrict__ out,
        int* __restrict__ codes_i, int* __restrict__ counts,
        double* __restrict__ lossAcc, int* __restrict__ flagC, int* __restrict__ flagR) {
    __shared__ float cs[NCODE];
    __shared__ int h[NCODE];
    __shared__ float A_s[128];
    __shared__ int code_s[128];
    __shared__ double ls[4];
    int tid = threadIdx.x;
    for (int i = tid; i < NCODE; i += 256) { cs[i] = csum[i]; h[i] = 0; }
    // A prepass: np-pairwise ||x||^2 for this block's 128 rows (verified bit path)
    if (tid < 128) {
        const float* xr = ze + (size_t)(blockIdx.x * 128 + tid) * DIM;
        float xv[DIM];
#pragma unroll
        for (int d = 0; d < DIM; d += 4) {
            float4 v = *reinterpret_cast<const float4*>(xr + d);
            xv[d] = v.x; xv[d + 1] = v.y; xv[d + 2] = v.z; xv[d + 3] = v.w;
        }
        A_s[tid] = np_pairwise64_sq(xv);
    }
    __syncthreads();

    int wid = tid >> 6;
    int lane = tid & 63;
    int r16 = lane & 15;
    int kg = lane >> 4;                 // k-group 0..3 (8 k-elements each)
    int rowbase = blockIdx.x * 128 + wid * 32;

    // per-lane A values for the 8 (rt,reg) output rows
    float Ar[2][4];
#pragma unroll
    for (int rt = 0; rt < 2; ++rt)
#pragma unroll
        for (int reg = 0; reg < 4; ++reg)
            Ar[rt][reg] = A_s[wid * 32 + rt * 16 + 4 * kg + reg];

    // A-fragments: [row-tile][k-half], hi and lo planes
    short8v ahi[2][2], alo[2][2];
#define LOADA(rt, hf) { \
        const float4* ap = reinterpret_cast<const float4*>( \
            ze + (size_t)(rowbase + (rt) * 16 + r16) * DIM + (hf) * 32 + 8 * kg); \
        float4 u = ap[0], w = ap[1]; \
        CVTE(ahi[rt][hf], alo[rt][hf], 0, u.x) CVTE(ahi[rt][hf], alo[rt][hf], 1, u.y) \
        CVTE(ahi[rt][hf], alo[rt][hf], 2, u.z) CVTE(ahi[rt][hf], alo[rt][hf], 3, u.w) \
        CVTE(ahi[rt][hf], alo[rt][hf], 4, w.x) CVTE(ahi[rt][hf], alo[rt][hf], 5, w.y) \
        CVTE(ahi[rt][hf], alo[rt][hf], 6, w.z) CVTE(ahi[rt][hf], alo[rt][hf], 7, w.w) }
    LOADA(0, 0) LOADA(0, 1) LOADA(1, 0) LOADA(1, 1)

    float m1v[2][4], m2v[2][4];
    int i1v[2][4];
#pragma unroll
    for (int rt = 0; rt < 2; ++rt)
#pragma unroll
        for (int j = 0; j < 4; ++j) { m1v[rt][j] = 3.4e38f; m2v[rt][j] = 3.4e38f; i1v[rt][j] = 0; }

    // np-chain emulation: t~ = fl(fl(A - 2*dot) + csum); dot = ca+cb, 2*dot = d+d exact
#define UPD(CA, CB, rt, reg) { \
        float dsum = __fadd_rn(CA[reg], CB[reg]); \
        float u = __fsub_rn(Ar[rt][reg], __fadd_rn(dsum, dsum)); \
        float s = __fadd_rn(u, csv); \
        if (s < m1v[rt][reg]) { m2v[rt][reg] = m1v[rt][reg]; m1v[rt][reg] = s; i1v[rt][reg] = codeIdx; } \
        else if (s < m2v[rt][reg]) { m2v[rt][reg] = s; } }

    for (int t = 0; t < 32; ++t) {
        const short8v* bh = reinterpret_cast<const short8v*>(
            ehi + (size_t)(t * 16 + r16) * DIM + 8 * kg);
        const short8v* bl = reinterpret_cast<const short8v*>(
            elo + (size_t)(t * 16 + r16) * DIM + 8 * kg);
        short8v bh0 = bh[0], bh1 = bh[4];      // k-half 0 (d 0..31), k-half 1 (d 32..63)
        short8v bl0 = bl[0], bl1 = bl[4];
        // split accumulators: two independent 3-chains per output tile
        f32x4 c0a = {0.f, 0.f, 0.f, 0.f}, c0b = {0.f, 0.f, 0.f, 0.f};
        f32x4 c1a = {0.f, 0.f, 0.f, 0.f}, c1b = {0.f, 0.f, 0.f, 0.f};
        c0a = __builtin_amdgcn_mfma_f32_16x16x32_bf16(ahi[0][0], bh0, c0a, 0, 0, 0);
        c0b = __builtin_amdgcn_mfma_f32_16x16x32_bf16(ahi[0][1], bh1, c0b, 0, 0, 0);
        c1a = __builtin_amdgcn_mfma_f32_16x16x32_bf16(ahi[1][0], bh0, c1a, 0, 0, 0);
        c1b = __builtin_amdgcn_mfma_f32_16x16x32_bf16(ahi[1][1], bh1, c1b, 0, 0, 0);
        c0a = __builtin_amdgcn_mfma_f32_16x16x32_bf16(alo[0][0], bh0, c0a, 0, 0, 0);
        c0b = __builtin_amdgcn_mfma_f32_16x16x32_bf16(alo[0][1], bh1, c0b, 0, 0, 0);
        c1a = __builtin_amdgcn_mfma_f32_16x16x32_bf16(alo[1][0], bh0, c1a, 0, 0, 0);
        c1b = __builtin_amdgcn_mfma_f32_16x16x32_bf16(alo[1][1], bh1, c1b, 0, 0, 0);
        c0a = __builtin_amdgcn_mfma_f32_16x16x32_bf16(ahi[0][0], bl0, c0a, 0, 0, 0);
        c0b = __builtin_amdgcn_mfma_f32_16x16x32_bf16(ahi[0][1], bl1, c0b, 0, 0, 0);
        c1a = __builtin_amdgcn_mfma_f32_16x16x32_bf16(ahi[1][0], bl0, c1a, 0, 0, 0);
        c1b = __builtin_amdgcn_mfma_f32_16x16x32_bf16(ahi[1][1], bl1, c1b, 0, 0, 0);
        float csv = cs[t * 16 + r16];
        int codeIdx = t * 16 + r16;
        UPD(c0a, c0b, 0, 0) UPD(c0a, c0b, 0, 1) UPD(c0a, c0b, 0, 2) UPD(c0a, c0b, 0, 3)
        UPD(c1a, c1b, 1, 0) UPD(c1a, c1b, 1, 1) UPD(c1a, c1b, 1, 2) UPD(c1a, c1b, 1, 3)
    }

    // reduce across the 16 lanes sharing a row (masks 1,2,4,8 stay in-group)
#define RED(rt, reg, mask) { \
        float om1 = __shfl_xor(m1v[rt][reg], mask); \
        int   oi  = __shfl_xor(i1v[rt][reg], mask); \
        float om2 = __shfl_xor(m2v[rt][reg], mask); \
        if (om1 < m1v[rt][reg]) { \
            m2v[rt][reg] = fminf(m1v[rt][reg], om2); m1v[rt][reg] = om1; i1v[rt][reg] = oi; \
        } else if (om1 > m1v[rt][reg]) { \
            m2v[rt][reg] = fminf(m2v[rt][reg], om1); \
        } else { \
            if (oi < i1v[rt][reg]) i1v[rt][reg] = oi; \
            m2v[rt][reg] = m1v[rt][reg]; } }
#define RED4(rt, reg) RED(rt, reg, 1) RED(rt, reg, 2) RED(rt, reg, 4) RED(rt, reg, 8)
    RED4(0, 0) RED4(0, 1) RED4(0, 2) RED4(0, 3)
    RED4(1, 0) RED4(1, 1) RED4(1, 2) RED4(1, 3)

    if (r16 == 0) {
        // flag if margin <= 4 quanta of ulp(A): thr = A*6e-7 covers all attainable A
#define WOUT(rt, reg) { \
        int lrow = wid * 32 + (rt) * 16 + 4 * kg + (reg); \
        int row = blockIdx.x * 128 + lrow; \
        code_s[lrow] = i1v[rt][reg]; \
        out[OUT_CODES + row] = (float)i1v[rt][reg]; \
        codes_i[row] = i1v[rt][reg]; \
        atomicAdd(&h[i1v[rt][reg]], 1); \
        if (m2v[rt][reg] - m1v[rt][reg] < Ar[rt][reg] * 6e-7f) { \
            int pos = atomicAdd(flagC, 1); \
            if (pos < FLAG_CAP) flagR[pos] = row; } }
        WOUT(0, 0) WOUT(0, 1) WOUT(0, 2) WOUT(0, 3)
        WOUT(1, 0) WOUT(1, 1) WOUT(1, 2) WOUT(1, 3)
    }
    __syncthreads();                        // code_s + h complete

    // provisional z_q + loss (rescue patches changed rows later)
    double lpart = 0.0;
#pragma unroll 4
    for (int r = 0; r < 32; ++r) {
        int code = code_s[wid * 32 + r];    // wave-uniform broadcast
        int row = rowbase + r;
        float x = ze[(size_t)row * DIM + lane];
        float e = emb[(size_t)code * DIM + lane];
        float tdiff = __fsub_rn(e, x);
        out[OUT_ZQ + (size_t)row * DIM + lane] = __fadd_rn(x, tdiff);
        lpart += (double)tdiff * tdiff;
    }
    for (int off = 32; off; off >>= 1) lpart += __shfl_down(lpart, off);
    if (lane == 0) ls[wid] = lpart;
    __syncthreads();
    if (tid == 0) atomicAdd(lossAcc, (ls[0] + ls[1]) + (ls[2] + ls[3]));
    for (int k = tid; k < NCODE; k += 256) {
        int cc = h[k];
        if (cc) atomicAdd(&counts[k], cc);
    }
}

// ---- rescue: bit-exact np-f32 re-argmin of flagged rows; patch if changed ----
__global__ __launch_bounds__(64) void k_rescue(
        const float* __restrict__ ze, const float* __restrict__ emb,
        const float* __restrict__ csum, float* __restrict__ out,
        int* __restrict__ codes_i, int* __restrict__ counts,
        double* __restrict__ lossAcc, const int* __restrict__ flagC,
        const int* __restrict__ flagR) {
    __shared__ float x2s[DIM];
    int nf = *flagC;
    if (nf > FLAG_CAP) nf = FLAG_CAP;
    int lane = threadIdx.x;
    for (int i = blockIdx.x; i < nf; i += gridDim.x) {
        int row = flagR[i];
        __syncthreads();
        float v = ze[(size_t)row * DIM + lane];
        x2s[lane] = __fadd_rn(v, v);
        __syncthreads();
        float r[8];
#pragma unroll
        for (int j = 0; j < 8; ++j) r[j] = __fmul_rn(x2s[j], x2s[j]);
#pragma unroll
        for (int b = 1; b < 8; ++b) {
#pragma unroll
            for (int j = 0; j < 8; ++j)
                r[j] = __fadd_rn(r[j], __fmul_rn(x2s[8 * b + j], x2s[8 * b + j]));
        }
        float A = __fmul_rn(0.25f,
            __fadd_rn(__fadd_rn(__fadd_rn(r[0], r[1]), __fadd_rn(r[2], r[3])),
                      __fadd_rn(__fadd_rn(r[4], r[5]), __fadd_rn(r[6], r[7]))));
        float m1 = 3.4e38f;
        int i1 = 0x7fffffff;
#pragma unroll
        for (int kk = 0; kk < 8; ++kk) {        // ascending k within lane
            int k = lane * 8 + kk;
            const float* e = emb + (size_t)k * DIM;
            float a = 0.f;
#pragma unroll
            for (int d = 0; d < DIM; ++d) a = __builtin_fmaf(x2s[d], e[d], a);
            float t = __fadd_rn(__fsub_rn(A, a), csum[k]);
            if (t < m1) { m1 = t; i1 = k; }
        }
        for (int off = 32; off; off >>= 1) {    // butterfly min, lowest-index tie-break
            float ov = __shfl_xor(m1, off);
            int oi = __shfl_xor(i1, off);
            if (ov < m1 || (ov == m1 && oi < i1)) { m1 = ov; i1 = oi; }
        }
        int oldc = codes_i[row];
        if (i1 != oldc) {                       // patch provisional results
            if (lane == 0) {
                codes_i[row] = i1;
                out[OUT_CODES + row] = (float)i1;
                atomicSub(&counts[oldc], 1);
                atomicAdd(&counts[i1], 1);
            }
            float x = __fmul_rn(0.5f, x2s[lane]);
            float en = emb[(size_t)i1 * DIM + lane];
            float eo = emb[(size_t)oldc * DIM + lane];
            float tn = __fsub_rn(en, x);
            float to = __fsub_rn(eo, x);
            out[OUT_ZQ + (size_t)row * DIM + lane] = __fadd_rn(x, tn);
            double dl = (double)tn * tn - (double)to * to;
            for (int off = 32; off; off >>= 1) dl += __shfl_down(dl, off);
            if (lane == 0) atomicAdd(lossAcc, dl);
        }
    }
}

// ---- one block: exclusive scan of counts -> offsets/cursor; new_ecs + n ----
__global__ __launch_bounds__(512) void k_scan(
        const int* __restrict__ counts, int* __restrict__ offsets, int* __restrict__ cursor,
        const float* __restrict__ ecs_in, float* __restrict__ out, float* __restrict__ n_out) {
    __shared__ int sa[NCODE], sb[NCODE];
    __shared__ float red[NCODE];
    int k = threadIdx.x;
    int c = counts[k];
    sa[k] = c;
    float v = __fadd_rn(__fmul_rn(ecs_in[k], DECAY_C), __fmul_rn((float)c, OMD_C));
    out[OUT_ECS + k] = v;
    red[k] = v;
    __syncthreads();
    int* src = sa;
    int* dst = sb;
    for (int off = 1; off < NCODE; off <<= 1) {
        dst[k] = (k >= off) ? src[k - off] + src[k] : src[k];
        __syncthreads();
        int* tp = src; src = dst; dst = tp;
    }
    offsets[k] = src[k] - c;
    cursor[k]  = src[k] - c;
    for (int s = NCODE / 2; s > 0; s >>= 1) {
        if (k < s) red[k] += red[k + s];
        __syncthreads();
    }
    if (k == 0) n_out[0] = red[0];
}

// ---- scatter rows into code buckets ----
__global__ __launch_bounds__(256) void k_scatter(
        const int* __restrict__ codes_i, int* __restrict__ cursor, int* __restrict__ bucket) {
    int row = blockIdx.x * 256 + threadIdx.x;
    int c = codes_i[row];
    int pos = atomicAdd(&cursor[c], 1);
    bucket[pos] = row;
}

// ---- per-code segmented sum, 4 blocks per code -> dw4 partials (no atomics) ----
__global__ __launch_bounds__(256) void k_dw(
        const float* __restrict__ ze, const int* __restrict__ bucket,
        const int* __restrict__ offsets, const int* __restrict__ counts,
        float* __restrict__ dw4) {
    __shared__ float p[4][DIM];
    int k = blockIdx.x >> 2;
    int q = blockIdx.x & 3;
    int w = threadIdx.x >> 6;
    int d = threadIdx.x & 63;
    int s = offsets[k];
    int n = counts[k];
    float acc0 = 0.f, acc1 = 0.f;
    int i = q + 4 * w;
    for (; i + 16 < n; i += 32) {
        int ra = bucket[s + i];
        int rb = bucket[s + i + 16];
        acc0 += ze[(size_t)ra * DIM + d];
        acc1 += ze[(size_t)rb * DIM + d];
    }
    if (i < n) acc0 += ze[(size_t)bucket[s + i] * DIM + d];
    p[w][d] = acc0 + acc1;
    __syncthreads();
    if (w == 0) dw4[((size_t)q * NCODE + k) * DIM + d] = (p[0][d] + p[1][d]) + (p[2][d] + p[3][d]);
}

// ---- new_ema_w, new_emb, loss ----
__global__ __launch_bounds__(256) void k_final(
        const float* __restrict__ ema_w, const float* __restrict__ dw4,
        const float* __restrict__ n_ptr, const double* __restrict__ lossAcc,
        float* __restrict__ out) {
    int i = blockIdx.x * blockDim.x + threadIdx.x;
    if (i >= NCODE * DIM) return;
    int k = i >> 6;
    float dsum = __fadd_rn(__fadd_rn(dw4[i], dw4[i + NCODE * DIM]),
                           __fadd_rn(dw4[i + 2 * NCODE * DIM], dw4[i + 3 * NCODE * DIM]));
    float w = __fadd_rn(__fmul_rn(ema_w[i], DECAY_C), __fmul_rn(dsum, OMD_C));
    out[OUT_EMAW + i] = w;
    float n = n_ptr[0];
    float necs = out[OUT_ECS + k];
    float cs = (necs + EPS_C) / (n + (float)NCODE * EPS_C) * n;
    out[OUT_EMB + i] = w / (cs + EPS_C);
    if (i == 0) out[OUT_LOSS] = (float)(0.1 * (lossAcc[0] / (double)((size_t)NROWS * DIM)));
}

extern "C" void kernel_launch(void* const* d_in, const int* in_sizes, int n_in,
                              void* d_out, int out_size, void* d_ws, size_t ws_size,
                              hipStream_t stream) {
    const float* ze   = (const float*)d_in[0];
    const float* emb  = (const float*)d_in[1];
    const float* ecs  = (const float*)d_in[2];
    const float* emaw = (const float*)d_in[3];
    float* out = (float*)d_out;
    char* ws = (char*)d_ws;
    double* lossAcc = (double*)(ws + WS_LOSS);
    float*  n_out   = (float*)(ws + WS_N);
    int*    flagC   = (int*)(ws + WS_FLAGC);
    int*    counts  = (int*)(ws + WS_COUNTS);
    int*    offsets = (int*)(ws + WS_OFFSETS);
    int*    cursor  = (int*)(ws + WS_CURSOR);
    float*  csum    = (float*)(ws + WS_CSUM);
    unsigned short* ehi = (unsigned short*)(ws + WS_EHI);
    unsigned short* elo = (unsigned short*)(ws + WS_ELO);
    int*    codes_i = (int*)(ws + WS_CODESI);
    float*  dw4     = (float*)(ws + WS_DW4);     // aliases codes_i (k_dw after k_scatter)
    int*    bucket  = (int*)(ws + WS_BUCKET);
    int*    flagR   = (int*)(ws + WS_FLAGR);     // aliases bucket (dead before k_scatter)

    hipLaunchKernelGGL(k_csum, dim3(2), dim3(256), 0, stream,
                       emb, csum, ehi, elo, counts, flagC, lossAcc, n_out);
    hipLaunchKernelGGL(k_mfma, dim3(NROWS / 128), dim3(256), 0, stream,
                       ze, emb, ehi, elo, csum, out, codes_i, counts, lossAcc, flagC, flagR);
    hipLaunchKernelGGL(k_rescue, dim3(2048), dim3(64), 0, stream,
                       ze, emb, csum, out, codes_i, counts, lossAcc, flagC, flagR);
    hipLaunchKernelGGL(k_scan, dim3(1), dim3(512), 0, stream,
                       counts, offsets, cursor, ecs, out, n_out);
    hipLaunchKernelGGL(k_scatter, dim3(NROWS / 256), dim3(256), 0, stream,
                       codes_i, cursor, bucket);
    hipLaunchKernelGGL(k_dw, dim3(NCODE * 4), dim3(256), 0, stream,
                       ze, bucket, offsets, counts, dw4);
    hipLaunchKernelGGL(k_final, dim3(NCODE * DIM / 256), dim3(256), 0, stream,
                       emaw, dw4, n_out, lossAcc, out);
}

// Round 18
// 212.661 us; speedup vs baseline: 1.3765x; 1.1243x over previous
//
#include <hip/hip_runtime.h>
#include <math.h>

// VQ-VAE EMA vector quantizer for MI355X (gfx950).
// Round 18: REVERT k_mfma to the round-13 champion (118us): 32 rows/wave, 1024 blocks,
// __launch_bounds__(256,1), single 6-deep MFMA chains, VGPR=64 (exactly on the HW
// occupancy step — rounds 14-17 proved every perturbation regresses: reg-dbuf +20VGPR
// -> occ halves; (256,8) -> 32-VGPR spill; 16 rows/wave -> overhead; chain split
// +8 VGPR -> occ step). np-chain emulation t~ = fl(fl(A-2dot)+csum) with quantized
// flag margin (< 4 ulp(A)); bit-exact np-f32 rescue patches flagged rows.
// k_csum keeps the folded zeroing+bf16-split (tail-side, orthogonal).
#define NROWS 131072          // 32*4096
#define DIM 64
#define NCODE 512
#define FLAG_CAP 32768

// d_out float offsets
#define OUT_ZQ    0
#define OUT_LOSS  8388608
#define OUT_CODES 8388609
#define OUT_ECS   8519681
#define OUT_EMAW  8520193
#define OUT_EMB   8552961

// workspace byte offsets
#define WS_LOSS    0         // double
#define WS_N       8         // float
#define WS_FLAGC   12        // int
#define WS_COUNTS  16        // int[512]
#define WS_OFFSETS 2064      // int[512]
#define WS_CURSOR  4112      // int[512]
#define WS_CSUM    6160      // float[512]
#define WS_EHI     8208      // ushort[512*64]
#define WS_ELO     73744     // ushort[512*64]
#define WS_CODESI  139280    // int[131072]; dead after k_scatter -> reused as dw4
#define WS_DW4     139280    // float[4*512*64]
#define WS_BUCKET  663568    // int[131072]; before k_scatter reused as flagR
#define WS_FLAGR   663568
#define WS_BYTES   1187856

#define DECAY_C ((float)0.9)
#define OMD_C   ((float)(1.0 - 0.9))
#define EPS_C   ((float)1e-5)

typedef float f32x4 __attribute__((ext_vector_type(4)));
typedef short short8v __attribute__((ext_vector_type(8)));

__device__ __forceinline__ unsigned short bf16_rne_bits(float f) {
    unsigned int u = __float_as_uint(f);
    unsigned int r = u + 0x7fffu + ((u >> 16) & 1u);
    return (unsigned short)(r >> 16);
}

// numpy pairwise sum (scalar unroll-8 path, n=64) of v[d]*v[d], f32, no contraction.
__device__ __forceinline__ float np_pairwise64_sq(const float* v) {
    float r[8];
#pragma unroll
    for (int j = 0; j < 8; ++j) r[j] = __fmul_rn(v[j], v[j]);
#pragma unroll
    for (int b = 1; b < 8; ++b) {
#pragma unroll
        for (int j = 0; j < 8; ++j)
            r[j] = __fadd_rn(r[j], __fmul_rn(v[8 * b + j], v[8 * b + j]));
    }
    return __fadd_rn(__fadd_rn(__fadd_rn(r[0], r[1]), __fadd_rn(r[2], r[3])),
                     __fadd_rn(__fadd_rn(r[4], r[5]), __fadd_rn(r[6], r[7])));
}

// ---- csum + bf16 split + workspace zeroing (memset dispatch folded in) ----
__global__ void k_csum(const float* __restrict__ emb, float* __restrict__ csum,
                       unsigned short* __restrict__ ehi, unsigned short* __restrict__ elo,
                       int* __restrict__ counts, int* __restrict__ flagC,
                       double* __restrict__ lossAcc, float* __restrict__ n_out) {
    int k = blockIdx.x * blockDim.x + threadIdx.x;
    if (k >= NCODE) return;
    counts[k] = 0;
    if (k == 0) { *flagC = 0; *lossAcc = 0.0; *n_out = 0.f; }
    float e[DIM];
#pragma unroll
    for (int d = 0; d < DIM; d += 4) {
        float4 v = *reinterpret_cast<const float4*>(emb + (size_t)k * DIM + d);
        e[d] = v.x; e[d + 1] = v.y; e[d + 2] = v.z; e[d + 3] = v.w;
    }
    csum[k] = np_pairwise64_sq(e);
#pragma unroll
    for (int d = 0; d < DIM; ++d) {
        unsigned short hb = bf16_rne_bits(e[d]);
        float hf = __uint_as_float((unsigned int)hb << 16);
        ehi[k * DIM + d] = hb;
        elo[k * DIM + d] = bf16_rne_bits(e[d] - hf);
    }
}

#define CVTE(H, L, j, val) { \
    unsigned int ub = __float_as_uint(val); \
    unsigned int rr = ub + 0x7fffu + ((ub >> 16) & 1u); \
    unsigned short hb = (unsigned short)(rr >> 16); \
    float hf2 = __uint_as_float(((unsigned int)hb) << 16); \
    float lof = (val) - hf2; \
    unsigned int ul = __float_as_uint(lof); \
    unsigned int rl = ul + 0x7fffu + ((ul >> 16) & 1u); \
    H[j] = (short)hb; L[j] = (short)(rl >> 16); }

// ---- MFMA scores (np-chain emulated) + fused z_q/loss/hist; 32 rows/wave ----
__global__ __launch_bounds__(256, 1) void k_mfma(
        const float* __restrict__ ze, const float* __restrict__ emb,
        const unsigned short* __restrict__ ehi, const unsigned short* __restrict__ elo,
        const float* __restrict__ csum, float* __restrict__ out,
        int* __restrict__ codes_i, int* __restrict__ counts,
        double* __restrict__ lossAcc, int* __restrict__ flagC, int* __restrict__ flagR) {
    __shared__ float cs[NCODE];
    __shared__ int h[NCODE];
    __shared__ float A_s[128];
    __shared__ int code_s[128];
    __shared__ double ls[4];
    int tid = threadIdx.x;
    for (int i = tid; i < NCODE; i += 256) { cs[i] = csum[i]; h[i] = 0; }
    // A prepass: np-pairwise ||x||^2 for this block's 128 rows (verified bit path)
    if (tid < 128) {
        const float* xr = ze + (size_t)(blockIdx.x * 128 + tid) * DIM;
        float xv[DIM];
#pragma unroll
        for (int d = 0; d < DIM; d += 4) {
            float4 v = *reinterpret_cast<const float4*>(xr + d);
            xv[d] = v.x; xv[d + 1] = v.y; xv[d + 2] = v.z; xv[d + 3] = v.w;
        }
        A_s[tid] = np_pairwise64_sq(xv);
    }
    __syncthreads();

    int wid = tid >> 6;
    int lane = tid & 63;
    int r16 = lane & 15;
    int kg = lane >> 4;                 // k-group 0..3 (8 k-elements each)
    int rowbase = blockIdx.x * 128 + wid * 32;

    // per-lane A values for the 8 (rt,reg) output rows
    float Ar[2][4];
#pragma unroll
    for (int rt = 0; rt < 2; ++rt)
#pragma unroll
        for (int reg = 0; reg < 4; ++reg)
            Ar[rt][reg] = A_s[wid * 32 + rt * 16 + 4 * kg + reg];

    // A-fragments: [row-tile][k-half], hi and lo planes
    short8v ahi[2][2], alo[2][2];
#define LOADA(rt, hf) { \
        const float4* ap = reinterpret_cast<const float4*>( \
            ze + (size_t)(rowbase + (rt) * 16 + r16) * DIM + (hf) * 32 + 8 * kg); \
        float4 u = ap[0], w = ap[1]; \
        CVTE(ahi[rt][hf], alo[rt][hf], 0, u.x) CVTE(ahi[rt][hf], alo[rt][hf], 1, u.y) \
        CVTE(ahi[rt][hf], alo[rt][hf], 2, u.z) CVTE(ahi[rt][hf], alo[rt][hf], 3, u.w) \
        CVTE(ahi[rt][hf], alo[rt][hf], 4, w.x) CVTE(ahi[rt][hf], alo[rt][hf], 5, w.y) \
        CVTE(ahi[rt][hf], alo[rt][hf], 6, w.z) CVTE(ahi[rt][hf], alo[rt][hf], 7, w.w) }
    LOADA(0, 0) LOADA(0, 1) LOADA(1, 0) LOADA(1, 1)

    float m1v[2][4], m2v[2][4];
    int i1v[2][4];
#pragma unroll
    for (int rt = 0; rt < 2; ++rt)
#pragma unroll
        for (int j = 0; j < 4; ++j) { m1v[rt][j] = 3.4e38f; m2v[rt][j] = 3.4e38f; i1v[rt][j] = 0; }

    // np-chain emulation: t~ = fl(fl(A - 2*dot) + csum); 2*dot = c+c exact
#define UPD(C, rt, reg) { \
        float u = __fsub_rn(Ar[rt][reg], __fadd_rn(C[reg], C[reg])); \
        float s = __fadd_rn(u, csv); \
        if (s < m1v[rt][reg]) { m2v[rt][reg] = m1v[rt][reg]; m1v[rt][reg] = s; i1v[rt][reg] = codeIdx; } \
        else if (s < m2v[rt][reg]) { m2v[rt][reg] = s; } }

    for (int t = 0; t < 32; ++t) {
        const short8v* bh = reinterpret_cast<const short8v*>(
            ehi + (size_t)(t * 16 + r16) * DIM + 8 * kg);
        const short8v* bl = reinterpret_cast<const short8v*>(
            elo + (size_t)(t * 16 + r16) * DIM + 8 * kg);
        short8v bh0 = bh[0], bh1 = bh[4];      // k-half 0 (d 0..31), k-half 1 (d 32..63)
        short8v bl0 = bl[0], bl1 = bl[4];
        f32x4 c0 = {0.f, 0.f, 0.f, 0.f};
        f32x4 c1 = {0.f, 0.f, 0.f, 0.f};
        c0 = __builtin_amdgcn_mfma_f32_16x16x32_bf16(ahi[0][0], bh0, c0, 0, 0, 0);
        c0 = __builtin_amdgcn_mfma_f32_16x16x32_bf16(ahi[0][1], bh1, c0, 0, 0, 0);
        c0 = __builtin_amdgcn_mfma_f32_16x16x32_bf16(alo[0][0], bh0, c0, 0, 0, 0);
        c0 = __builtin_amdgcn_mfma_f32_16x16x32_bf16(alo[0][1], bh1, c0, 0, 0, 0);
        c0 = __builtin_amdgcn_mfma_f32_16x16x32_bf16(ahi[0][0], bl0, c0, 0, 0, 0);
        c0 = __builtin_amdgcn_mfma_f32_16x16x32_bf16(ahi[0][1], bl1, c0, 0, 0, 0);
        c1 = __builtin_amdgcn_mfma_f32_16x16x32_bf16(ahi[1][0], bh0, c1, 0, 0, 0);
        c1 = __builtin_amdgcn_mfma_f32_16x16x32_bf16(ahi[1][1], bh1, c1, 0, 0, 0);
        c1 = __builtin_amdgcn_mfma_f32_16x16x32_bf16(alo[1][0], bh0, c1, 0, 0, 0);
        c1 = __builtin_amdgcn_mfma_f32_16x16x32_bf16(alo[1][1], bh1, c1, 0, 0, 0);
        c1 = __builtin_amdgcn_mfma_f32_16x16x32_bf16(ahi[1][0], bl0, c1, 0, 0, 0);
        c1 = __builtin_amdgcn_mfma_f32_16x16x32_bf16(ahi[1][1], bl1, c1, 0, 0, 0);
        float csv = cs[t * 16 + r16];
        int codeIdx = t * 16 + r16;
        UPD(c0, 0, 0) UPD(c0, 0, 1) UPD(c0, 0, 2) UPD(c0, 0, 3)
        UPD(c1, 1, 0) UPD(c1, 1, 1) UPD(c1, 1, 2) UPD(c1, 1, 3)
    }

    // reduce across the 16 lanes sharing a row (masks 1,2,4,8 stay in-group)
#define RED(rt, reg, mask) { \
        float om1 = __shfl_xor(m1v[rt][reg], mask); \
        int   oi  = __shfl_xor(i1v[rt][reg], mask); \
        float om2 = __shfl_xor(m2v[rt][reg], mask); \
        if (om1 < m1v[rt][reg]) { \
            m2v[rt][reg] = fminf(m1v[rt][reg], om2); m1v[rt][reg] = om1; i1v[rt][reg] = oi; \
        } else if (om1 > m1v[rt][reg]) { \
            m2v[rt][reg] = fminf(m2v[rt][reg], om1); \
        } else { \
            if (oi < i1v[rt][reg]) i1v[rt][reg] = oi; \
            m2v[rt][reg] = m1v[rt][reg]; } }
#define RED4(rt, reg) RED(rt, reg, 1) RED(rt, reg, 2) RED(rt, reg, 4) RED(rt, reg, 8)
    RED4(0, 0) RED4(0, 1) RED4(0, 2) RED4(0, 3)
    RED4(1, 0) RED4(1, 1) RED4(1, 2) RED4(1, 3)

    if (r16 == 0) {
        // flag if margin <= 4 quanta of ulp(A): thr = A*6e-7 covers all attainable A
#define WOUT(rt, reg) { \
        int lrow = wid * 32 + (rt) * 16 + 4 * kg + (reg); \
        int row = blockIdx.x * 128 + lrow; \
        code_s[lrow] = i1v[rt][reg]; \
        out[OUT_CODES + row] = (float)i1v[rt][reg]; \
        codes_i[row] = i1v[rt][reg]; \
        atomicAdd(&h[i1v[rt][reg]], 1); \
        if (m2v[rt][reg] - m1v[rt][reg] < Ar[rt][reg] * 6e-7f) { \
            int pos = atomicAdd(flagC, 1); \
            if (pos < FLAG_CAP) flagR[pos] = row; } }
        WOUT(0, 0) WOUT(0, 1) WOUT(0, 2) WOUT(0, 3)
        WOUT(1, 0) WOUT(1, 1) WOUT(1, 2) WOUT(1, 3)
    }
    __syncthreads();                        // code_s + h complete

    // provisional z_q + loss (rescue patches changed rows later)
    double lpart = 0.0;
#pragma unroll 4
    for (int r = 0; r < 32; ++r) {
        int code = code_s[wid * 32 + r];    // wave-uniform broadcast
        int row = rowbase + r;
        float x = ze[(size_t)row * DIM + lane];
        float e = emb[(size_t)code * DIM + lane];
        float tdiff = __fsub_rn(e, x);
        out[OUT_ZQ + (size_t)row * DIM + lane] = __fadd_rn(x, tdiff);
        lpart += (double)tdiff * tdiff;
    }
    for (int off = 32; off; off >>= 1) lpart += __shfl_down(lpart, off);
    if (lane == 0) ls[wid] = lpart;
    __syncthreads();
    if (tid == 0) atomicAdd(lossAcc, (ls[0] + ls[1]) + (ls[2] + ls[3]));
    for (int k = tid; k < NCODE; k += 256) {
        int cc = h[k];
        if (cc) atomicAdd(&counts[k], cc);
    }
}

// ---- rescue: bit-exact np-f32 re-argmin of flagged rows; patch if changed ----
__global__ __launch_bounds__(64) void k_rescue(
        const float* __restrict__ ze, const float* __restrict__ emb,
        const float* __restrict__ csum, float* __restrict__ out,
        int* __restrict__ codes_i, int* __restrict__ counts,
        double* __restrict__ lossAcc, const int* __restrict__ flagC,
        const int* __restrict__ flagR) {
    __shared__ float x2s[DIM];
    int nf = *flagC;
    if (nf > FLAG_CAP) nf = FLAG_CAP;
    int lane = threadIdx.x;
    for (int i = blockIdx.x; i < nf; i += gridDim.x) {
        int row = flagR[i];
        __syncthreads();
        float v = ze[(size_t)row * DIM + lane];
        x2s[lane] = __fadd_rn(v, v);
        __syncthreads();
        float r[8];
#pragma unroll
        for (int j = 0; j < 8; ++j) r[j] = __fmul_rn(x2s[j], x2s[j]);
#pragma unroll
        for (int b = 1; b < 8; ++b) {
#pragma unroll
            for (int j = 0; j < 8; ++j)
                r[j] = __fadd_rn(r[j], __fmul_rn(x2s[8 * b + j], x2s[8 * b + j]));
        }
        float A = __fmul_rn(0.25f,
            __fadd_rn(__fadd_rn(__fadd_rn(r[0], r[1]), __fadd_rn(r[2], r[3])),
                      __fadd_rn(__fadd_rn(r[4], r[5]), __fadd_rn(r[6], r[7]))));
        float m1 = 3.4e38f;
        int i1 = 0x7fffffff;
#pragma unroll
        for (int kk = 0; kk < 8; ++kk) {        // ascending k within lane
            int k = lane * 8 + kk;
            const float* e = emb + (size_t)k * DIM;
            float a = 0.f;
#pragma unroll
            for (int d = 0; d < DIM; ++d) a = __builtin_fmaf(x2s[d], e[d], a);
            float t = __fadd_rn(__fsub_rn(A, a), csum[k]);
            if (t < m1) { m1 = t; i1 = k; }
        }
        for (int off = 32; off; off >>= 1) {    // butterfly min, lowest-index tie-break
            float ov = __shfl_xor(m1, off);
            int oi = __shfl_xor(i1, off);
            if (ov < m1 || (ov == m1 && oi < i1)) { m1 = ov; i1 = oi; }
        }
        int oldc = codes_i[row];
        if (i1 != oldc) {                       // patch provisional results
            if (lane == 0) {
                codes_i[row] = i1;
                out[OUT_CODES + row] = (float)i1;
                atomicSub(&counts[oldc], 1);
                atomicAdd(&counts[i1], 1);
            }
            float x = __fmul_rn(0.5f, x2s[lane]);
            float en = emb[(size_t)i1 * DIM + lane];
            float eo = emb[(size_t)oldc * DIM + lane];
            float tn = __fsub_rn(en, x);
            float to = __fsub_rn(eo, x);
            out[OUT_ZQ + (size_t)row * DIM + lane] = __fadd_rn(x, tn);
            double dl = (double)tn * tn - (double)to * to;
            for (int off = 32; off; off >>= 1) dl += __shfl_down(dl, off);
            if (lane == 0) atomicAdd(lossAcc, dl);
        }
    }
}

// ---- one block: exclusive scan of counts -> offsets/cursor; new_ecs + n ----
__global__ __launch_bounds__(512) void k_scan(
        const int* __restrict__ counts, int* __restrict__ offsets, int* __restrict__ cursor,
        const float* __restrict__ ecs_in, float* __restrict__ out, float* __restrict__ n_out) {
    __shared__ int sa[NCODE], sb[NCODE];
    __shared__ float red[NCODE];
    int k = threadIdx.x;
    int c = counts[k];
    sa[k] = c;
    float v = __fadd_rn(__fmul_rn(ecs_in[k], DECAY_C), __fmul_rn((float)c, OMD_C));
    out[OUT_ECS + k] = v;
    red[k] = v;
    __syncthreads();
    int* src = sa;
    int* dst = sb;
    for (int off = 1; off < NCODE; off <<= 1) {
        dst[k] = (k >= off) ? src[k - off] + src[k] : src[k];
        __syncthreads();
        int* tp = src; src = dst; dst = tp;
    }
    offsets[k] = src[k] - c;
    cursor[k]  = src[k] - c;
    for (int s = NCODE / 2; s > 0; s >>= 1) {
        if (k < s) red[k] += red[k + s];
        __syncthreads();
    }
    if (k == 0) n_out[0] = red[0];
}

// ---- scatter rows into code buckets ----
__global__ __launch_bounds__(256) void k_scatter(
        const int* __restrict__ codes_i, int* __restrict__ cursor, int* __restrict__ bucket) {
    int row = blockIdx.x * 256 + threadIdx.x;
    int c = codes_i[row];
    int pos = atomicAdd(&cursor[c], 1);
    bucket[pos] = row;
}

// ---- per-code segmented sum, 4 blocks per code -> dw4 partials (no atomics) ----
__global__ __launch_bounds__(256) void k_dw(
        const float* __restrict__ ze, const int* __restrict__ bucket,
        const int* __restrict__ offsets, const int* __restrict__ counts,
        float* __restrict__ dw4) {
    __shared__ float p[4][DIM];
    int k = blockIdx.x >> 2;
    int q = blockIdx.x & 3;
    int w = threadIdx.x >> 6;
    int d = threadIdx.x & 63;
    int s = offsets[k];
    int n = counts[k];
    float acc0 = 0.f, acc1 = 0.f;
    int i = q + 4 * w;
    for (; i + 16 < n; i += 32) {
        int ra = bucket[s + i];
        int rb = bucket[s + i + 16];
        acc0 += ze[(size_t)ra * DIM + d];
        acc1 += ze[(size_t)rb * DIM + d];
    }
    if (i < n) acc0 += ze[(size_t)bucket[s + i] * DIM + d];
    p[w][d] = acc0 + acc1;
    __syncthreads();
    if (w == 0) dw4[((size_t)q * NCODE + k) * DIM + d] = (p[0][d] + p[1][d]) + (p[2][d] + p[3][d]);
}

// ---- new_ema_w, new_emb, loss ----
__global__ __launch_bounds__(256) void k_final(
        const float* __restrict__ ema_w, const float* __restrict__ dw4,
        const float* __restrict__ n_ptr, const double* __restrict__ lossAcc,
        float* __restrict__ out) {
    int i = blockIdx.x * blockDim.x + threadIdx.x;
    if (i >= NCODE * DIM) return;
    int k = i >> 6;
    float dsum = __fadd_rn(__fadd_rn(dw4[i], dw4[i + NCODE * DIM]),
                           __fadd_rn(dw4[i + 2 * NCODE * DIM], dw4[i + 3 * NCODE * DIM]));
    float w = __fadd_rn(__fmul_rn(ema_w[i], DECAY_C), __fmul_rn(dsum, OMD_C));
    out[OUT_EMAW + i] = w;
    float n = n_ptr[0];
    float necs = out[OUT_ECS + k];
    float cs = (necs + EPS_C) / (n + (float)NCODE * EPS_C) * n;
    out[OUT_EMB + i] = w / (cs + EPS_C);
    if (i == 0) out[OUT_LOSS] = (float)(0.1 * (lossAcc[0] / (double)((size_t)NROWS * DIM)));
}

extern "C" void kernel_launch(void* const* d_in, const int* in_sizes, int n_in,
                              void* d_out, int out_size, void* d_ws, size_t ws_size,
                              hipStream_t stream) {
    const float* ze   = (const float*)d_in[0];
    const float* emb  = (const float*)d_in[1];
    const float* ecs  = (const float*)d_in[2];
    const float* emaw = (const float*)d_in[3];
    float* out = (float*)d_out;
    char* ws = (char*)d_ws;
    double* lossAcc = (double*)(ws + WS_LOSS);
    float*  n_out   = (float*)(ws + WS_N);
    int*    flagC   = (int*)(ws + WS_FLAGC);
    int*    counts  = (int*)(ws + WS_COUNTS);
    int*    offsets = (int*)(ws + WS_OFFSETS);
    int*    cursor  = (int*)(ws + WS_CURSOR);
    float*  csum    = (float*)(ws + WS_CSUM);
    unsigned short* ehi = (unsigned short*)(ws + WS_EHI);
    unsigned short* elo = (unsigned short*)(ws + WS_ELO);
    int*    codes_i = (int*)(ws + WS_CODESI);
    float*  dw4     = (float*)(ws + WS_DW4);     // aliases codes_i (k_dw after k_scatter)
    int*    bucket  = (int*)(ws + WS_BUCKET);
    int*    flagR   = (int*)(ws + WS_FLAGR);     // aliases bucket (dead before k_scatter)

    hipLaunchKernelGGL(k_csum, dim3(2), dim3(256), 0, stream,
                       emb, csum, ehi, elo, counts, flagC, lossAcc, n_out);
    hipLaunchKernelGGL(k_mfma, dim3(NROWS / 128), dim3(256), 0, stream,
                       ze, emb, ehi, elo, csum, out, codes_i, counts, lossAcc, flagC, flagR);
    hipLaunchKernelGGL(k_rescue, dim3(2048), dim3(64), 0, stream,
                       ze, emb, csum, out, codes_i, counts, lossAcc, flagC, flagR);
    hipLaunchKernelGGL(k_scan, dim3(1), dim3(512), 0, stream,
                       counts, offsets, cursor, ecs, out, n_out);
    hipLaunchKernelGGL(k_scatter, dim3(NROWS / 256), dim3(256), 0, stream,
                       codes_i, cursor, bucket);
    hipLaunchKernelGGL(k_dw, dim3(NCODE * 4), dim3(256), 0, stream,
                       ze, bucket, offsets, counts, dw4);
    hipLaunchKernelGGL(k_final, dim3(NCODE * DIM / 256), dim3(256), 0, stream,
                       emaw, dw4, n_out, lossAcc, out);
}

// Round 19
// 207.993 us; speedup vs baseline: 1.4074x; 1.0224x over previous
//
#include <hip/hip_runtime.h>
#include <math.h>

// VQ-VAE EMA vector quantizer for MI355X (gfx950).
// Round 19: k_mfma = round-13 champion (untouched: 32 rows/wave, (256,1), VGPR=64).
// Rescue fixes: (a) flag threshold tightened to its provable minimum A*3e-7
// (>=2.4 score-quanta in all binades; worst-case mfma-vs-np dot deviation is
// ~0.12 quanta, so margin > 2 quanta is exact-safe) — halves the ~25% flag rate;
// (b) k_rescue at 4 waves/block, per-wave LDS slice, float4 emb loads;
// (c) FLAG_CAP = 131072 (full flagR region) — removes silent-truncation hazard.
#define NROWS 131072          // 32*4096
#define DIM 64
#define NCODE 512
#define FLAG_CAP 131072

// d_out float offsets
#define OUT_ZQ    0
#define OUT_LOSS  8388608
#define OUT_CODES 8388609
#define OUT_ECS   8519681
#define OUT_EMAW  8520193
#define OUT_EMB   8552961

// workspace byte offsets
#define WS_LOSS    0         // double
#define WS_N       8         // float
#define WS_FLAGC   12        // int
#define WS_COUNTS  16        // int[512]
#define WS_OFFSETS 2064      // int[512]
#define WS_CURSOR  4112      // int[512]
#define WS_CSUM    6160      // float[512]
#define WS_EHI     8208      // ushort[512*64]
#define WS_ELO     73744     // ushort[512*64]
#define WS_CODESI  139280    // int[131072]; dead after k_scatter -> reused as dw4
#define WS_DW4     139280    // float[4*512*64]
#define WS_BUCKET  663568    // int[131072]; before k_scatter reused as flagR
#define WS_FLAGR   663568
#define WS_BYTES   1187856

#define DECAY_C ((float)0.9)
#define OMD_C   ((float)(1.0 - 0.9))
#define EPS_C   ((float)1e-5)

typedef float f32x4 __attribute__((ext_vector_type(4)));
typedef short short8v __attribute__((ext_vector_type(8)));

__device__ __forceinline__ unsigned short bf16_rne_bits(float f) {
    unsigned int u = __float_as_uint(f);
    unsigned int r = u + 0x7fffu + ((u >> 16) & 1u);
    return (unsigned short)(r >> 16);
}

// numpy pairwise sum (scalar unroll-8 path, n=64) of v[d]*v[d], f32, no contraction.
__device__ __forceinline__ float np_pairwise64_sq(const float* v) {
    float r[8];
#pragma unroll
    for (int j = 0; j < 8; ++j) r[j] = __fmul_rn(v[j], v[j]);
#pragma unroll
    for (int b = 1; b < 8; ++b) {
#pragma unroll
        for (int j = 0; j < 8; ++j)
            r[j] = __fadd_rn(r[j], __fmul_rn(v[8 * b + j], v[8 * b + j]));
    }
    return __fadd_rn(__fadd_rn(__fadd_rn(r[0], r[1]), __fadd_rn(r[2], r[3])),
                     __fadd_rn(__fadd_rn(r[4], r[5]), __fadd_rn(r[6], r[7])));
}

// ---- csum + bf16 split + workspace zeroing (memset dispatch folded in) ----
__global__ void k_csum(const float* __restrict__ emb, float* __restrict__ csum,
                       unsigned short* __restrict__ ehi, unsigned short* __restrict__ elo,
                       int* __restrict__ counts, int* __restrict__ flagC,
                       double* __restrict__ lossAcc, float* __restrict__ n_out) {
    int k = blockIdx.x * blockDim.x + threadIdx.x;
    if (k >= NCODE) return;
    counts[k] = 0;
    if (k == 0) { *flagC = 0; *lossAcc = 0.0; *n_out = 0.f; }
    float e[DIM];
#pragma unroll
    for (int d = 0; d < DIM; d += 4) {
        float4 v = *reinterpret_cast<const float4*>(emb + (size_t)k * DIM + d);
        e[d] = v.x; e[d + 1] = v.y; e[d + 2] = v.z; e[d + 3] = v.w;
    }
    csum[k] = np_pairwise64_sq(e);
#pragma unroll
    for (int d = 0; d < DIM; ++d) {
        unsigned short hb = bf16_rne_bits(e[d]);
        float hf = __uint_as_float((unsigned int)hb << 16);
        ehi[k * DIM + d] = hb;
        elo[k * DIM + d] = bf16_rne_bits(e[d] - hf);
    }
}

#define CVTE(H, L, j, val) { \
    unsigned int ub = __float_as_uint(val); \
    unsigned int rr = ub + 0x7fffu + ((ub >> 16) & 1u); \
    unsigned short hb = (unsigned short)(rr >> 16); \
    float hf2 = __uint_as_float(((unsigned int)hb) << 16); \
    float lof = (val) - hf2; \
    unsigned int ul = __float_as_uint(lof); \
    unsigned int rl = ul + 0x7fffu + ((ul >> 16) & 1u); \
    H[j] = (short)hb; L[j] = (short)(rl >> 16); }

// ---- MFMA scores (np-chain emulated) + fused z_q/loss/hist; 32 rows/wave ----
__global__ __launch_bounds__(256, 1) void k_mfma(
        const float* __restrict__ ze, const float* __restrict__ emb,
        const unsigned short* __restrict__ ehi, const unsigned short* __restrict__ elo,
        const float* __restrict__ csum, float* __restrict__ out,
        int* __restrict__ codes_i, int* __restrict__ counts,
        double* __restrict__ lossAcc, int* __restrict__ flagC, int* __restrict__ flagR) {
    __shared__ float cs[NCODE];
    __shared__ int h[NCODE];
    __shared__ float A_s[128];
    __shared__ int code_s[128];
    __shared__ double ls[4];
    int tid = threadIdx.x;
    for (int i = tid; i < NCODE; i += 256) { cs[i] = csum[i]; h[i] = 0; }
    // A prepass: np-pairwise ||x||^2 for this block's 128 rows (verified bit path)
    if (tid < 128) {
        const float* xr = ze + (size_t)(blockIdx.x * 128 + tid) * DIM;
        float xv[DIM];
#pragma unroll
        for (int d = 0; d < DIM; d += 4) {
            float4 v = *reinterpret_cast<const float4*>(xr + d);
            xv[d] = v.x; xv[d + 1] = v.y; xv[d + 2] = v.z; xv[d + 3] = v.w;
        }
        A_s[tid] = np_pairwise64_sq(xv);
    }
    __syncthreads();

    int wid = tid >> 6;
    int lane = tid & 63;
    int r16 = lane & 15;
    int kg = lane >> 4;                 // k-group 0..3 (8 k-elements each)
    int rowbase = blockIdx.x * 128 + wid * 32;

    // per-lane A values for the 8 (rt,reg) output rows
    float Ar[2][4];
#pragma unroll
    for (int rt = 0; rt < 2; ++rt)
#pragma unroll
        for (int reg = 0; reg < 4; ++reg)
            Ar[rt][reg] = A_s[wid * 32 + rt * 16 + 4 * kg + reg];

    // A-fragments: [row-tile][k-half], hi and lo planes
    short8v ahi[2][2], alo[2][2];
#define LOADA(rt, hf) { \
        const float4* ap = reinterpret_cast<const float4*>( \
            ze + (size_t)(rowbase + (rt) * 16 + r16) * DIM + (hf) * 32 + 8 * kg); \
        float4 u = ap[0], w = ap[1]; \
        CVTE(ahi[rt][hf], alo[rt][hf], 0, u.x) CVTE(ahi[rt][hf], alo[rt][hf], 1, u.y) \
        CVTE(ahi[rt][hf], alo[rt][hf], 2, u.z) CVTE(ahi[rt][hf], alo[rt][hf], 3, u.w) \
        CVTE(ahi[rt][hf], alo[rt][hf], 4, w.x) CVTE(ahi[rt][hf], alo[rt][hf], 5, w.y) \
        CVTE(ahi[rt][hf], alo[rt][hf], 6, w.z) CVTE(ahi[rt][hf], alo[rt][hf], 7, w.w) }
    LOADA(0, 0) LOADA(0, 1) LOADA(1, 0) LOADA(1, 1)

    float m1v[2][4], m2v[2][4];
    int i1v[2][4];
#pragma unroll
    for (int rt = 0; rt < 2; ++rt)
#pragma unroll
        for (int j = 0; j < 4; ++j) { m1v[rt][j] = 3.4e38f; m2v[rt][j] = 3.4e38f; i1v[rt][j] = 0; }

    // np-chain emulation: t~ = fl(fl(A - 2*dot) + csum); 2*dot = c+c exact
#define UPD(C, rt, reg) { \
        float u = __fsub_rn(Ar[rt][reg], __fadd_rn(C[reg], C[reg])); \
        float s = __fadd_rn(u, csv); \
        if (s < m1v[rt][reg]) { m2v[rt][reg] = m1v[rt][reg]; m1v[rt][reg] = s; i1v[rt][reg] = codeIdx; } \
        else if (s < m2v[rt][reg]) { m2v[rt][reg] = s; } }

    for (int t = 0; t < 32; ++t) {
        const short8v* bh = reinterpret_cast<const short8v*>(
            ehi + (size_t)(t * 16 + r16) * DIM + 8 * kg);
        const short8v* bl = reinterpret_cast<const short8v*>(
            elo + (size_t)(t * 16 + r16) * DIM + 8 * kg);
        short8v bh0 = bh[0], bh1 = bh[4];      // k-half 0 (d 0..31), k-half 1 (d 32..63)
        short8v bl0 = bl[0], bl1 = bl[4];
        f32x4 c0 = {0.f, 0.f, 0.f, 0.f};
        f32x4 c1 = {0.f, 0.f, 0.f, 0.f};
        c0 = __builtin_amdgcn_mfma_f32_16x16x32_bf16(ahi[0][0], bh0, c0, 0, 0, 0);
        c0 = __builtin_amdgcn_mfma_f32_16x16x32_bf16(ahi[0][1], bh1, c0, 0, 0, 0);
        c0 = __builtin_amdgcn_mfma_f32_16x16x32_bf16(alo[0][0], bh0, c0, 0, 0, 0);
        c0 = __builtin_amdgcn_mfma_f32_16x16x32_bf16(alo[0][1], bh1, c0, 0, 0, 0);
        c0 = __builtin_amdgcn_mfma_f32_16x16x32_bf16(ahi[0][0], bl0, c0, 0, 0, 0);
        c0 = __builtin_amdgcn_mfma_f32_16x16x32_bf16(ahi[0][1], bl1, c0, 0, 0, 0);
        c1 = __builtin_amdgcn_mfma_f32_16x16x32_bf16(ahi[1][0], bh0, c1, 0, 0, 0);
        c1 = __builtin_amdgcn_mfma_f32_16x16x32_bf16(ahi[1][1], bh1, c1, 0, 0, 0);
        c1 = __builtin_amdgcn_mfma_f32_16x16x32_bf16(alo[1][0], bh0, c1, 0, 0, 0);
        c1 = __builtin_amdgcn_mfma_f32_16x16x32_bf16(alo[1][1], bh1, c1, 0, 0, 0);
        c1 = __builtin_amdgcn_mfma_f32_16x16x32_bf16(ahi[1][0], bl0, c1, 0, 0, 0);
        c1 = __builtin_amdgcn_mfma_f32_16x16x32_bf16(ahi[1][1], bl1, c1, 0, 0, 0);
        float csv = cs[t * 16 + r16];
        int codeIdx = t * 16 + r16;
        UPD(c0, 0, 0) UPD(c0, 0, 1) UPD(c0, 0, 2) UPD(c0, 0, 3)
        UPD(c1, 1, 0) UPD(c1, 1, 1) UPD(c1, 1, 2) UPD(c1, 1, 3)
    }

    // reduce across the 16 lanes sharing a row (masks 1,2,4,8 stay in-group)
#define RED(rt, reg, mask) { \
        float om1 = __shfl_xor(m1v[rt][reg], mask); \
        int   oi  = __shfl_xor(i1v[rt][reg], mask); \
        float om2 = __shfl_xor(m2v[rt][reg], mask); \
        if (om1 < m1v[rt][reg]) { \
            m2v[rt][reg] = fminf(m1v[rt][reg], om2); m1v[rt][reg] = om1; i1v[rt][reg] = oi; \
        } else if (om1 > m1v[rt][reg]) { \
            m2v[rt][reg] = fminf(m2v[rt][reg], om1); \
        } else { \
            if (oi < i1v[rt][reg]) i1v[rt][reg] = oi; \
            m2v[rt][reg] = m1v[rt][reg]; } }
#define RED4(rt, reg) RED(rt, reg, 1) RED(rt, reg, 2) RED(rt, reg, 4) RED(rt, reg, 8)
    RED4(0, 0) RED4(0, 1) RED4(0, 2) RED4(0, 3)
    RED4(1, 0) RED4(1, 1) RED4(1, 2) RED4(1, 3)

    if (r16 == 0) {
        // flag if margin < A*3e-7 (>= 2.4 score-quanta in every binade — provably
        // covers the <=1-quantum-per-score deviation of the emulated chain)
#define WOUT(rt, reg) { \
        int lrow = wid * 32 + (rt) * 16 + 4 * kg + (reg); \
        int row = blockIdx.x * 128 + lrow; \
        code_s[lrow] = i1v[rt][reg]; \
        out[OUT_CODES + row] = (float)i1v[rt][reg]; \
        codes_i[row] = i1v[rt][reg]; \
        atomicAdd(&h[i1v[rt][reg]], 1); \
        if (m2v[rt][reg] - m1v[rt][reg] < Ar[rt][reg] * 3e-7f) { \
            int pos = atomicAdd(flagC, 1); \
            if (pos < FLAG_CAP) flagR[pos] = row; } }
        WOUT(0, 0) WOUT(0, 1) WOUT(0, 2) WOUT(0, 3)
        WOUT(1, 0) WOUT(1, 1) WOUT(1, 2) WOUT(1, 3)
    }
    __syncthreads();                        // code_s + h complete

    // provisional z_q + loss (rescue patches changed rows later)
    double lpart = 0.0;
#pragma unroll 4
    for (int r = 0; r < 32; ++r) {
        int code = code_s[wid * 32 + r];    // wave-uniform broadcast
        int row = rowbase + r;
        float x = ze[(size_t)row * DIM + lane];
        float e = emb[(size_t)code * DIM + lane];
        float tdiff = __fsub_rn(e, x);
        out[OUT_ZQ + (size_t)row * DIM + lane] = __fadd_rn(x, tdiff);
        lpart += (double)tdiff * tdiff;
    }
    for (int off = 32; off; off >>= 1) lpart += __shfl_down(lpart, off);
    if (lane == 0) ls[wid] = lpart;
    __syncthreads();
    if (tid == 0) atomicAdd(lossAcc, (ls[0] + ls[1]) + (ls[2] + ls[3]));
    for (int k = tid; k < NCODE; k += 256) {
        int cc = h[k];
        if (cc) atomicAdd(&counts[k], cc);
    }
}

// ---- rescue: bit-exact np-f32 re-argmin of flagged rows; 4 waves/block ----
__global__ __launch_bounds__(256) void k_rescue(
        const float* __restrict__ ze, const float* __restrict__ emb,
        const float* __restrict__ csum, float* __restrict__ out,
        int* __restrict__ codes_i, int* __restrict__ counts,
        double* __restrict__ lossAcc, const int* __restrict__ flagC,
        const int* __restrict__ flagR) {
    __shared__ float xs[4][DIM];            // per-wave row slice (wave-coherent, no barrier)
    int nf = *flagC;
    if (nf > FLAG_CAP) nf = FLAG_CAP;
    int w = threadIdx.x >> 6;
    int lane = threadIdx.x & 63;
    for (int i = blockIdx.x * 4 + w; i < nf; i += gridDim.x * 4) {
        int row = flagR[i];
        float v = ze[(size_t)row * DIM + lane];
        xs[w][lane] = __fadd_rn(v, v);
        __builtin_amdgcn_wave_barrier();    // order LDS write before cross-lane reads
        float r[8];
#pragma unroll
        for (int j = 0; j < 8; ++j) r[j] = __fmul_rn(xs[w][j], xs[w][j]);
#pragma unroll
        for (int b = 1; b < 8; ++b) {
#pragma unroll
            for (int j = 0; j < 8; ++j)
                r[j] = __fadd_rn(r[j], __fmul_rn(xs[w][8 * b + j], xs[w][8 * b + j]));
        }
        float A = __fmul_rn(0.25f,
            __fadd_rn(__fadd_rn(__fadd_rn(r[0], r[1]), __fadd_rn(r[2], r[3])),
                      __fadd_rn(__fadd_rn(r[4], r[5]), __fadd_rn(r[6], r[7]))));
        float m1 = 3.4e38f;
        int i1 = 0x7fffffff;
#pragma unroll
        for (int kk = 0; kk < 8; ++kk) {        // ascending k within lane
            int k = lane * 8 + kk;
            const float4* e4 = reinterpret_cast<const float4*>(emb + (size_t)k * DIM);
            float a = 0.f;
#pragma unroll
            for (int j = 0; j < 16; ++j) {      // float4 loads; sequential FMA chain kept
                float4 ev = e4[j];
                a = __builtin_fmaf(xs[w][4 * j + 0], ev.x, a);
                a = __builtin_fmaf(xs[w][4 * j + 1], ev.y, a);
                a = __builtin_fmaf(xs[w][4 * j + 2], ev.z, a);
                a = __builtin_fmaf(xs[w][4 * j + 3], ev.w, a);
            }
            float t = __fadd_rn(__fsub_rn(A, a), csum[k]);
            if (t < m1) { m1 = t; i1 = k; }
        }
        for (int off = 32; off; off >>= 1) {    // butterfly min, lowest-index tie-break
            float ov = __shfl_xor(m1, off);
            int oi = __shfl_xor(i1, off);
            if (ov < m1 || (ov == m1 && oi < i1)) { m1 = ov; i1 = oi; }
        }
        int oldc = codes_i[row];
        if (i1 != oldc) {                       // patch provisional results
            if (lane == 0) {
                codes_i[row] = i1;
                out[OUT_CODES + row] = (float)i1;
                atomicSub(&counts[oldc], 1);
                atomicAdd(&counts[i1], 1);
            }
            float x = __fmul_rn(0.5f, xs[w][lane]);
            float en = emb[(size_t)i1 * DIM + lane];
            float eo = emb[(size_t)oldc * DIM + lane];
            float tn = __fsub_rn(en, x);
            float to = __fsub_rn(eo, x);
            out[OUT_ZQ + (size_t)row * DIM + lane] = __fadd_rn(x, tn);
            double dl = (double)tn * tn - (double)to * to;
            for (int off = 32; off; off >>= 1) dl += __shfl_down(dl, off);
            if (lane == 0) atomicAdd(lossAcc, dl);
        }
        __builtin_amdgcn_wave_barrier();        // next iter overwrites xs[w]
    }
}

// ---- one block: exclusive scan of counts -> offsets/cursor; new_ecs + n ----
__global__ __launch_bounds__(512) void k_scan(
        const int* __restrict__ counts, int* __restrict__ offsets, int* __restrict__ cursor,
        const float* __restrict__ ecs_in, float* __restrict__ out, float* __restrict__ n_out) {
    __shared__ int sa[NCODE], sb[NCODE];
    __shared__ float red[NCODE];
    int k = threadIdx.x;
    int c = counts[k];
    sa[k] = c;
    float v = __fadd_rn(__fmul_rn(ecs_in[k], DECAY_C), __fmul_rn((float)c, OMD_C));
    out[OUT_ECS + k] = v;
    red[k] = v;
    __syncthreads();
    int* src = sa;
    int* dst = sb;
    for (int off = 1; off < NCODE; off <<= 1) {
        dst[k] = (k >= off) ? src[k - off] + src[k] : src[k];
        __syncthreads();
        int* tp = src; src = dst; dst = tp;
    }
    offsets[k] = src[k] - c;
    cursor[k]  = src[k] - c;
    for (int s = NCODE / 2; s > 0; s >>= 1) {
        if (k < s) red[k] += red[k + s];
        __syncthreads();
    }
    if (k == 0) n_out[0] = red[0];
}

// ---- scatter rows into code buckets ----
__global__ __launch_bounds__(256) void k_scatter(
        const int* __restrict__ codes_i, int* __restrict__ cursor, int* __restrict__ bucket) {
    int row = blockIdx.x * 256 + threadIdx.x;
    int c = codes_i[row];
    int pos = atomicAdd(&cursor[c], 1);
    bucket[pos] = row;
}

// ---- per-code segmented sum, 4 blocks per code -> dw4 partials (no atomics) ----
__global__ __launch_bounds__(256) void k_dw(
        const float* __restrict__ ze, const int* __restrict__ bucket,
        const int* __restrict__ offsets, const int* __restrict__ counts,
        float* __restrict__ dw4) {
    __shared__ float p[4][DIM];
    int k = blockIdx.x >> 2;
    int q = blockIdx.x & 3;
    int w = threadIdx.x >> 6;
    int d = threadIdx.x & 63;
    int s = offsets[k];
    int n = counts[k];
    float acc0 = 0.f, acc1 = 0.f;
    int i = q + 4 * w;
    for (; i + 16 < n; i += 32) {
        int ra = bucket[s + i];
        int rb = bucket[s + i + 16];
        acc0 += ze[(size_t)ra * DIM + d];
        acc1 += ze[(size_t)rb * DIM + d];
    }
    if (i < n) acc0 += ze[(size_t)bucket[s + i] * DIM + d];
    p[w][d] = acc0 + acc1;
    __syncthreads();
    if (w == 0) dw4[((size_t)q * NCODE + k) * DIM + d] = (p[0][d] + p[1][d]) + (p[2][d] + p[3][d]);
}

// ---- new_ema_w, new_emb, loss ----
__global__ __launch_bounds__(256) void k_final(
        const float* __restrict__ ema_w, const float* __restrict__ dw4,
        const float* __restrict__ n_ptr, const double* __restrict__ lossAcc,
        float* __restrict__ out) {
    int i = blockIdx.x * blockDim.x + threadIdx.x;
    if (i >= NCODE * DIM) return;
    int k = i >> 6;
    float dsum = __fadd_rn(__fadd_rn(dw4[i], dw4[i + NCODE * DIM]),
                           __fadd_rn(dw4[i + 2 * NCODE * DIM], dw4[i + 3 * NCODE * DIM]));
    float w = __fadd_rn(__fmul_rn(ema_w[i], DECAY_C), __fmul_rn(dsum, OMD_C));
    out[OUT_EMAW + i] = w;
    float n = n_ptr[0];
    float necs = out[OUT_ECS + k];
    float cs = (necs + EPS_C) / (n + (float)NCODE * EPS_C) * n;
    out[OUT_EMB + i] = w / (cs + EPS_C);
    if (i == 0) out[OUT_LOSS] = (float)(0.1 * (lossAcc[0] / (double)((size_t)NROWS * DIM)));
}

extern "C" void kernel_launch(void* const* d_in, const int* in_sizes, int n_in,
                              void* d_out, int out_size, void* d_ws, size_t ws_size,
                              hipStream_t stream) {
    const float* ze   = (const float*)d_in[0];
    const float* emb  = (const float*)d_in[1];
    const float* ecs  = (const float*)d_in[2];
    const float* emaw = (const float*)d_in[3];
    float* out = (float*)d_out;
    char* ws = (char*)d_ws;
    double* lossAcc = (double*)(ws + WS_LOSS);
    float*  n_out   = (float*)(ws + WS_N);
    int*    flagC   = (int*)(ws + WS_FLAGC);
    int*    counts  = (int*)(ws + WS_COUNTS);
    int*    offsets = (int*)(ws + WS_OFFSETS);
    int*    cursor  = (int*)(ws + WS_CURSOR);
    float*  csum    = (float*)(ws + WS_CSUM);
    unsigned short* ehi = (unsigned short*)(ws + WS_EHI);
    unsigned short* elo = (unsigned short*)(ws + WS_ELO);
    int*    codes_i = (int*)(ws + WS_CODESI);
    float*  dw4     = (float*)(ws + WS_DW4);     // aliases codes_i (k_dw after k_scatter)
    int*    bucket  = (int*)(ws + WS_BUCKET);
    int*    flagR   = (int*)(ws + WS_FLAGR);     // aliases bucket (dead before k_scatter)

    hipLaunchKernelGGL(k_csum, dim3(2), dim3(256), 0, stream,
                       emb, csum, ehi, elo, counts, flagC, lossAcc, n_out);
    hipLaunchKernelGGL(k_mfma, dim3(NROWS / 128), dim3(256), 0, stream,
                       ze, emb, ehi, elo, csum, out, codes_i, counts, lossAcc, flagC, flagR);
    hipLaunchKernelGGL(k_rescue, dim3(1024), dim3(256), 0, stream,
                       ze, emb, csum, out, codes_i, counts, lossAcc, flagC, flagR);
    hipLaunchKernelGGL(k_scan, dim3(1), dim3(512), 0, stream,
                       counts, offsets, cursor, ecs, out, n_out);
    hipLaunchKernelGGL(k_scatter, dim3(NROWS / 256), dim3(256), 0, stream,
                       codes_i, cursor, bucket);
    hipLaunchKernelGGL(k_dw, dim3(NCODE * 4), dim3(256), 0, stream,
                       ze, bucket, offsets, counts, dw4);
    hipLaunchKernelGGL(k_final, dim3(NCODE * DIM / 256), dim3(256), 0, stream,
                       emaw, dw4, n_out, lossAcc, out);
}